// Round 7
// baseline (1304.833 us; speedup 1.0000x reference)
//
#include <hip/hip_runtime.h>
#include <hip/hip_bf16.h>
#include <stdint.h>

// FT-Transformer forward, MI355X gfx950. Round 12:
//  - NEW gemm_ln: fuses {GEMM + bias + residual -> h} with the FOLLOWING LayerNorm
//    (-> ab frag) in one kernel. Block = 32 rows x full N=512, 8 waves (wave 32x64,
//    acc 32 f32/thr). GEMM loop is BARRIER-FREE: A rows shared across waves ->
//    redundant direct loads (L1-hot, 32KB/block); B cols wave-private -> direct
//    loads (L2-pinned weight, 0.5-0.7MB shared by all 516 blocks); in-place depth-1
//    reload. Epilogue: h=acc+bias+resid (fp32 RW), LN over full row via quad-shuffle
//    + 2KB LDS cross-wave reduce, ab bf16 frag write. CLS out fused into last W1.
//    Eliminates all 11 ln_kernel dispatches + out_copy + ~370MB HBM h-re-reads.
//  - QKV / W0 keep round-11 gemm_frag (A-direct + B 2-buf LDS). attn unchanged.

typedef __hip_bfloat16 bf16_t;
typedef __attribute__((ext_vector_type(8))) __bf16 bf16x8;
typedef __attribute__((ext_vector_type(4))) __bf16 bf16x4;
typedef __attribute__((ext_vector_type(2))) __bf16 bf16x2;
typedef __attribute__((ext_vector_type(4))) float floatx4;

constexpr int M_ROWS = 16512;          // 128 * 129
constexpr float SQRT_EMB_F = 22.627416997969522f;  // scores DIVIDED by emb**-0.5

__device__ __forceinline__ floatx4 mfma16(bf16x8 a, bf16x8 b, floatx4 c) {
  return __builtin_amdgcn_mfma_f32_16x16x32_bf16(a, b, c, 0, 0, 0);
}

__device__ __forceinline__ void gload_lds16(const bf16_t* g, bf16_t* l) {
  __builtin_amdgcn_global_load_lds(
      (const __attribute__((address_space(1))) void*)g,
      (__attribute__((address_space(3))) void*)l, 16, 0, 0);
}

// element offset of the 16B chunk holding (m, k..k+7) in fragment-tiled [M/16][KT][512]
__device__ __forceinline__ size_t frag_chunk(int m, int k, int KT) {
  return ((size_t)(m >> 4) * KT + (k >> 5)) * 512 + (m & 15) * 8 + 128 * ((k >> 3) & 3);
}
// element offset of scalar (m, k)
__device__ __forceinline__ size_t frag_elem(int m, int k, int KT) {
  return frag_chunk(m, k, KT) + (k & 7);
}

// ---------------- weight transform: W [L][K][N] fp32 -> frag-tiled bf16 [L][N/16][KP/32][512]
// PERM=1: output col n maps to source col (n&1) ? 682+(n>>1) : (n>>1)  (ReGLU pairing)
template <int PERM>
__global__ __launch_bounds__(256) void transpose_cvt(const float* __restrict__ W,
    bf16_t* __restrict__ WT, int K, int N, int KP, int NP)
{
  __shared__ float tile[32][33];
  int k0 = blockIdx.x * 32, n0 = blockIdx.y * 32;
  const float* Wl = W + (size_t)blockIdx.z * K * N;
  bf16_t* WTl = WT + (size_t)blockIdx.z * NP * KP;
  const int KT = KP >> 5;
  #pragma unroll
  for (int r = 0; r < 32; r += 8) {
    int k = k0 + threadIdx.y + r, n = n0 + threadIdx.x;
    int srcn = PERM ? ((n & 1) ? 682 + (n >> 1) : (n >> 1)) : n;
    int valid = (k < K) && (PERM ? (n < 1364) : (n < N));
    tile[threadIdx.y + r][threadIdx.x] = valid ? Wl[(size_t)k * N + srcn] : 0.f;
  }
  __syncthreads();
  #pragma unroll
  for (int r = 0; r < 32; r += 8) {
    int n = n0 + threadIdx.y + r, k = k0 + threadIdx.x;
    if (n < NP && k < KP)
      WTl[frag_elem(n, k, KT)] = __float2bfloat16(tile[threadIdx.x][threadIdx.y + r]);
  }
}

// ---------------- feature tokenizer: wave per row; h row-major fp32 + ab frag bf16 ----------------
__global__ __launch_bounds__(256) void tokenizer_kernel(const float* __restrict__ x,
    const float* __restrict__ tok_w, const float* __restrict__ tok_b,
    const float* __restrict__ cat_emb, float* __restrict__ h, bf16_t* __restrict__ ab)
{
  int row = blockIdx.x * 4 + (threadIdx.x >> 6);
  int lane = threadIdx.x & 63, e0 = lane * 8;
  int b = row / 129, t = row - b * 129;
  float v[8];
  if (t == 0) {
    #pragma unroll
    for (int u = 0; u < 8; u++) v[u] = tok_w[e0 + u];
  } else if (t <= 100) {
    float xv = x[(size_t)b * 128 + 28 + (t - 1)];
    const float* wp = tok_w + (size_t)t * 512 + e0;
    const float* bp = tok_b + (size_t)(t - 1) * 512 + e0;
    #pragma unroll
    for (int u = 0; u < 8; u++) v[u] = wp[u] * xv + bp[u];
  } else {
    int j = t - 101;
    int idx = (int)x[(size_t)b * 128 + j] + 100 * j;
    const float* cp = cat_emb + (size_t)idx * 512 + e0;
    const float* bp = tok_b + (size_t)(t - 1) * 512 + e0;
    #pragma unroll
    for (int u = 0; u < 8; u++) v[u] = cp[u] + bp[u];
  }
  float* hr = h + (size_t)row * 512 + e0;
  #pragma unroll
  for (int u = 0; u < 8; u++) hr[u] = v[u];
  bf16x8 o8;
  #pragma unroll
  for (int u = 0; u < 8; u++) o8[u] = (__bf16)__float2bfloat16(v[u]);
  *(bf16x8*)(ab + ((size_t)(row >> 4) * 16 + (lane >> 2)) * 512 + (row & 15) * 8 + 128 * (lane & 3)) = o8;
}

// ---------------- frag GEMM (QKV / W0): 128x128 block, 4 waves, A-direct + B 2-buf LDS ----------------
// MODE 0: out bf16 frag-tiled (KT_out = N/32).
// MODE 2: ReGLU pairs thread-local, out bf16 frag-tiled [M/16][(N/2)/32][512].
template <int MODE>
__global__ __launch_bounds__(256, 4) void gemm_frag(const bf16_t* __restrict__ A,
    const bf16_t* __restrict__ BT, const float* __restrict__ bias, int biasN,
    const float* __restrict__ resid, void* __restrict__ outp, int K, int N)
{
  __shared__ bf16_t lsB[2][8][512];   // 16 KB

  // XCD-aware remap: blocks with lin%8==x get a contiguous idx chunk
  const int total = gridDim.x * gridDim.y;
  const int lin = blockIdx.y * gridDim.x + blockIdx.x;
  const int xcd = lin & 7, kb2 = lin >> 3;
  const int qch = total >> 3, rch = total & 7;
  const int idx = xcd * qch + (xcd < rch ? xcd : rch) + kb2;
  const int bm = idx / gridDim.x;
  const int bn = idx - bm * gridDim.x;
  const int m0 = bm * 128, n0 = bn * 128;

  const int tid = threadIdx.x;
  const int w = tid >> 6, l = tid & 63, l15 = l & 15, quad = l >> 4;
  const int wm = (w >> 1) * 64, wn = (w & 1) * 64;
  const int KT = K >> 5;

  // A direct: wave's 4 private row-fragments
  const bf16_t* pa[4];
  #pragma unroll
  for (int i = 0; i < 4; i++)
    pa[i] = A + ((size_t)((m0 >> 4) + (w >> 1) * 4 + i) * KT) * 512 + l * 8;

  // B staging: wave w stages B-tiles {2w, 2w+1}
  const bf16_t* gB0 = BT + ((size_t)((n0 >> 4) + 2 * w) * KT) * 512 + l * 8;
  const bf16_t* gB1 = gB0 + (size_t)KT * 512;
  const int sb = w * 2;
  const int rb = (w & 1) * 4;

  auto stageB = [&](int buf, int t) {
    const size_t go = (size_t)t * 512;
    gload_lds16(gB0 + go, &lsB[buf][sb][0]);
    gload_lds16(gB1 + go, &lsB[buf][sb + 1][0]);
  };

  floatx4 z4 = {0.f, 0.f, 0.f, 0.f};
  floatx4 acc[4][4];
  #pragma unroll
  for (int i = 0; i < 4; i++)
    #pragma unroll
    for (int j = 0; j < 4; j++) acc[i][j] = z4;

  bf16x8 af[4];
  #pragma unroll
  for (int i = 0; i < 4; i++) af[i] = *(const bf16x8*)pa[i];   // t=0
  stageB(0, 0);
  __syncthreads();   // drains vmcnt(0): buf0 + af ready

  int cur = 0;
  for (int t = 0; t < KT; ++t) {
    if (t + 1 < KT) stageB(cur ^ 1, t + 1);   // async DMA, lands during this step
    bf16x8 bg[4];
    #pragma unroll
    for (int j = 0; j < 4; j++) bg[j] = *(const bf16x8*)&lsB[cur][rb + j][l * 8];
    #pragma unroll
    for (int i = 0; i < 4; i++) {
      #pragma unroll
      for (int j = 0; j < 4; j++)
        acc[i][j] = mfma16(bg[j], af[i], acc[i][j]);   // C^T
      if (t + 1 < KT)
        af[i] = *(const bf16x8*)(pa[i] + (size_t)(t + 1) * 512);  // in-place reload
    }
    __syncthreads();   // guards lsB buf reuse (drains vmcnt)
    cur ^= 1;
  }

  // epilogue: thread owns rows m = m0+wm+i*16+l15, cols nb..nb+3 (consecutive)
  #pragma unroll
  for (int i = 0; i < 4; i++) {
    int m = m0 + wm + i * 16 + l15;
    #pragma unroll
    for (int j = 0; j < 4; j++) {
      int nb = n0 + wn + j * 16 + quad * 4;
      if (MODE == 2) {
        int c2b = nb >> 1;
        bf16x2 o2;
        #pragma unroll
        for (int u = 0; u < 2; u++) {
          int c2 = c2b + u;
          bool vld = (2 * c2 < biasN);
          float av = acc[i][j][2 * u]     + (vld ? bias[c2] : 0.f);
          float bv = acc[i][j][2 * u + 1] + (vld ? bias[682 + c2] : 0.f);
          o2[u] = (__bf16)__float2bfloat16(av * fmaxf(bv, 0.f));
        }
        *(bf16x2*)&((bf16_t*)outp)[frag_elem(m, c2b, (N >> 1) >> 5)] = o2;
      } else {
        bf16x4 o4;
        #pragma unroll
        for (int r = 0; r < 4; r++) {
          float bv = (nb + r < biasN) ? bias[nb + r] : 0.f;
          o4[r] = (__bf16)__float2bfloat16(acc[i][j][r] + bv);
        }
        *(bf16x4*)&((bf16_t*)outp)[frag_elem(m, nb, N >> 5)] = o4;
      }
    }
  }
  (void)resid;
}

// ---------------- fused GEMM + residual + LayerNorm: 32 rows x full N=512 ----------------
// C = A * BT^T + bias + resid -> h (fp32); then LN(h) -> ab (bf16 frag, KT=16).
// 8 waves; wave tile 32x64 (acc 32 f32/thr). Barrier-free GEMM: A rows shared (L1-hot
// redundant direct loads), B cols wave-private (L2-hot direct loads), depth-1 in-place
// reload. LN: quad shuffles + 2KB LDS cross-wave reduce.
// DOLN=0: skip LN/ab. DOOUT=1: also write CLS rows (m%129==0) to outp.
template <int DOLN, int DOOUT>
__global__ __launch_bounds__(512, 4) void gemm_ln(const bf16_t* __restrict__ A,
    const bf16_t* __restrict__ BT, const float* __restrict__ bias,
    const float* __restrict__ resid, float* __restrict__ hout,
    const float* __restrict__ g, const float* __restrict__ beta,
    bf16_t* __restrict__ ab, float* __restrict__ outp, int K)
{
  __shared__ float lnred[2][8][32];   // 2 KB

  // XCD-aware bijective remap (1-D grid)
  const int nwg = gridDim.x;
  const int lin = blockIdx.x;
  const int xcd = lin & 7, kb2 = lin >> 3;
  const int qch = nwg >> 3, rch = nwg & 7;
  const int idx = xcd * qch + (xcd < rch ? xcd : rch) + kb2;
  const int m0 = idx * 32;

  const int tid = threadIdx.x;
  const int w = tid >> 6, l = tid & 63, l15 = l & 15, quad = l >> 4;
  const int wn = w * 64;
  const int KT = K >> 5;

  const bf16_t* pa0 = A + ((size_t)(m0 >> 4) * KT) * 512 + l * 8;
  const bf16_t* pa1 = pa0 + (size_t)KT * 512;
  const bf16_t* pb[4];
  #pragma unroll
  for (int j = 0; j < 4; j++)
    pb[j] = BT + ((size_t)((wn >> 4) + j) * KT) * 512 + l * 8;

  floatx4 acc[2][4];
  #pragma unroll
  for (int i = 0; i < 2; i++)
    #pragma unroll
    for (int j = 0; j < 4; j++) acc[i][j] = floatx4{0.f, 0.f, 0.f, 0.f};

  bf16x8 af0 = *(const bf16x8*)pa0;
  bf16x8 af1 = *(const bf16x8*)pa1;
  bf16x8 bg[4];
  #pragma unroll
  for (int j = 0; j < 4; j++) bg[j] = *(const bf16x8*)pb[j];

  for (int t = 0; t < KT; ++t) {
    #pragma unroll
    for (int j = 0; j < 4; j++) {
      acc[0][j] = mfma16(bg[j], af0, acc[0][j]);   // C^T: l15 = row, quad*4+r = col
      acc[1][j] = mfma16(bg[j], af1, acc[1][j]);
      if (t + 1 < KT) bg[j] = *(const bf16x8*)(pb[j] + (size_t)(t + 1) * 512);
    }
    if (t + 1 < KT) {
      af0 = *(const bf16x8*)(pa0 + (size_t)(t + 1) * 512);
      af1 = *(const bf16x8*)(pa1 + (size_t)(t + 1) * 512);
    }
  }

  // ---- epilogue: h = acc + bias + resid; accumulate LN partials ----
  const int colb = wn + quad * 4;
  float s[2] = {0.f, 0.f}, q[2] = {0.f, 0.f};
  #pragma unroll
  for (int i = 0; i < 2; i++) {
    const int m = m0 + i * 16 + l15;
    float* hr = hout + (size_t)m * 512;
    const float* rr = resid + (size_t)m * 512;
    #pragma unroll
    for (int j = 0; j < 4; j++) {
      const int nb = colb + j * 16;
      float4 rv = *(const float4*)(rr + nb);
      float4 bv = *(const float4*)(bias + nb);
      floatx4 hv;
      hv[0] = acc[i][j][0] + bv.x + rv.x;
      hv[1] = acc[i][j][1] + bv.y + rv.y;
      hv[2] = acc[i][j][2] + bv.z + rv.z;
      hv[3] = acc[i][j][3] + bv.w + rv.w;
      acc[i][j] = hv;   // keep h values in acc (reg reuse)
      float4 hw = {hv[0], hv[1], hv[2], hv[3]};
      *(float4*)(hr + nb) = hw;
      if (DOOUT) {
        if (m % 129 == 0)
          *(float4*)(outp + (size_t)(m / 129) * 512 + nb) = hw;
      }
      s[i] += hv[0] + hv[1] + hv[2] + hv[3];
      q[i] += hv[0] * hv[0] + hv[1] * hv[1] + hv[2] * hv[2] + hv[3] * hv[3];
    }
  }

  if (DOLN) {
    // quad-reduce: lanes sharing l15 (4 quads) sum their 16-col partials
    #pragma unroll
    for (int i = 0; i < 2; i++) {
      s[i] += __shfl_xor(s[i], 16); s[i] += __shfl_xor(s[i], 32);
      q[i] += __shfl_xor(q[i], 16); q[i] += __shfl_xor(q[i], 32);
    }
    if (quad == 0) {
      lnred[0][w][l15]      = s[0];  lnred[1][w][l15]      = q[0];
      lnred[0][w][16 + l15] = s[1];  lnred[1][w][16 + l15] = q[1];
    }
    __syncthreads();
    #pragma unroll
    for (int i = 0; i < 2; i++) {
      const int m = m0 + i * 16 + l15;
      float ss = 0.f, qq = 0.f;
      #pragma unroll
      for (int wv = 0; wv < 8; wv++) {
        ss += lnred[0][wv][i * 16 + l15];
        qq += lnred[1][wv][i * 16 + l15];
      }
      float mean = ss * (1.f / 512.f);
      float var = qq * (1.f / 512.f) - mean * mean;
      float rstd = rsqrtf(var + 1e-5f);
      #pragma unroll
      for (int j = 0; j < 4; j++) {
        const int nb = colb + j * 16;
        float4 gg = *(const float4*)(g + nb);
        float4 bb = *(const float4*)(beta + nb);
        bf16x4 o4;
        o4[0] = (__bf16)__float2bfloat16((acc[i][j][0] - mean) * rstd * gg.x + bb.x);
        o4[1] = (__bf16)__float2bfloat16((acc[i][j][1] - mean) * rstd * gg.y + bb.y);
        o4[2] = (__bf16)__float2bfloat16((acc[i][j][2] - mean) * rstd * gg.z + bb.z);
        o4[3] = (__bf16)__float2bfloat16((acc[i][j][3] - mean) * rstd * gg.w + bb.w);
        *(bf16x4*)&ab[frag_elem(m, nb, 16)] = o4;
      }
    }
  }
}

// ---------------- fused attention: one block per (batch, head) ----------------
// qkv frag-tiled over [M, 1536] (KT=48); head hh: q at col hh*192, k +64, v +128.
constexpr int SP = 160;  // S=129 padded to 5*32
__global__ __launch_bounds__(256) void attn_kernel(const bf16_t* __restrict__ qkv,
                                                   bf16_t* __restrict__ attnout)
{
  __shared__ bf16_t vt_lds[64 * SP];   // [d][s_kv]
  __shared__ float sc[32 * SP];        // scores; p (bf16) overlays
  bf16_t* p_lds = (bf16_t*)sc;
  __bf16* vt_raw = (__bf16*)vt_lds;

  const int bh = blockIdx.x, b = bh >> 3, hh = bh & 7;
  const int tid = threadIdx.x;
  const int w = tid >> 6, l = tid & 63, l15 = l & 15, quad = l >> 4;
  const int rbase = b * 129;

  for (int i = tid; i < SP * 64 / 2; i += 256) ((unsigned int*)vt_lds)[i] = 0u;
  __syncthreads();
  for (int c = tid; c < 129 * 8; c += 256) {
    int s = c >> 3, ch = c & 7;
    bf16x8 tv = *(const bf16x8*)(qkv + frag_chunk(rbase + s, hh * 192 + 128 + ch * 8, 48));
    #pragma unroll
    for (int j = 0; j < 8; j++) vt_raw[(size_t)(ch * 8 + j) * SP + s] = tv[j];
  }
  __syncthreads();

  for (int qt = 0; qt < 5; qt++) {
    bf16x8 zq = {};
    bf16x8 aq[2][2];
    #pragma unroll
    for (int mt = 0; mt < 2; mt++) {
      int m = qt * 32 + mt * 16 + l15;
      #pragma unroll
      for (int t = 0; t < 2; t++)
        aq[mt][t] = (m < 129)
            ? *(const bf16x8*)(qkv + frag_chunk(rbase + m, hh * 192 + t * 32 + quad * 8, 48)) : zq;
    }
    for (int nt = w; nt < 10; nt += 4) {
      int krow = nt * 16 + l15;
      floatx4 a0 = {0.f, 0.f, 0.f, 0.f}, a1 = {0.f, 0.f, 0.f, 0.f};
      #pragma unroll
      for (int t = 0; t < 2; t++) {
        bf16x8 kf = (krow < 129)
            ? *(const bf16x8*)(qkv + frag_chunk(rbase + krow, hh * 192 + 64 + t * 32 + quad * 8, 48))
            : zq;
        a0 = mfma16(aq[0][t], kf, a0);
        a1 = mfma16(aq[1][t], kf, a1);
      }
      #pragma unroll
      for (int r = 0; r < 4; r++) {
        sc[(quad * 4 + r) * SP + nt * 16 + l15]      = a0[r] * SQRT_EMB_F;
        sc[(16 + quad * 4 + r) * SP + nt * 16 + l15] = a1[r] * SQRT_EMB_F;
      }
    }
    __syncthreads();

    // double softmax, 8 threads per row
    {
      int row = tid >> 3, sub = tid & 7;
      float vv[20];
      float mx = -1e30f;
      #pragma unroll
      for (int c = 0; c < 20; c++) {
        int j = sub + c * 8;
        vv[c] = (j < 129) ? sc[row * SP + j] : -1e30f;
        mx = fmaxf(mx, vv[c]);
      }
      #pragma unroll
      for (int o = 1; o < 8; o <<= 1) mx = fmaxf(mx, __shfl_xor(mx, o, 8));
      float sum = 0.f;
      #pragma unroll
      for (int c = 0; c < 20; c++) {
        int j = sub + c * 8;
        vv[c] = (j < 129) ? __expf(vv[c] - mx) : 0.f;
        sum += vv[c];
      }
      #pragma unroll
      for (int o = 1; o < 8; o <<= 1) sum += __shfl_xor(sum, o, 8);
      float inv = 1.f / sum;
      float mx2 = 0.f;
      #pragma unroll
      for (int c = 0; c < 20; c++) { vv[c] *= inv; mx2 = fmaxf(mx2, vv[c]); }
      #pragma unroll
      for (int o = 1; o < 8; o <<= 1) mx2 = fmaxf(mx2, __shfl_xor(mx2, o, 8));
      float sum2 = 0.f;
      #pragma unroll
      for (int c = 0; c < 20; c++) {
        int j = sub + c * 8;
        vv[c] = (j < 129) ? __expf(vv[c] - mx2) : 0.f;
        sum2 += vv[c];
      }
      #pragma unroll
      for (int o = 1; o < 8; o <<= 1) sum2 += __shfl_xor(sum2, o, 8);
      float inv2 = 1.f / sum2;
      __syncthreads();
      #pragma unroll
      for (int c = 0; c < 20; c++) {
        int j = sub + c * 8;
        p_lds[row * SP + j] = __float2bfloat16(vv[c] * inv2);  // pads -> 0
      }
    }
    __syncthreads();

    // PV: o[32,64] = p[32,160] @ v[160,64]; store attno in frag layout (KT=16)
    {
      int mt = w >> 1, nt0 = (w & 1) * 2;
      floatx4 oacc[2];
      oacc[0] = floatx4{0.f, 0.f, 0.f, 0.f};
      oacc[1] = floatx4{0.f, 0.f, 0.f, 0.f};
      #pragma unroll
      for (int t = 0; t < 5; t++) {
        bf16x8 pf = *(const bf16x8*)&p_lds[(mt * 16 + l15) * SP + t * 32 + quad * 8];
        #pragma unroll
        for (int n = 0; n < 2; n++) {
          bf16x8 vf = *(const bf16x8*)&vt_lds[((nt0 + n) * 16 + l15) * SP + t * 32 + quad * 8];
          oacc[n] = mfma16(pf, vf, oacc[n]);
        }
      }
      #pragma unroll
      for (int n = 0; n < 2; n++)
        #pragma unroll
        for (int r = 0; r < 4; r++) {
          int sq = qt * 32 + mt * 16 + quad * 4 + r;
          if (sq < 129) {
            int cc = hh * 64 + (nt0 + n) * 16 + l15;
            attnout[frag_elem(rbase + sq, cc, 16)] = __float2bfloat16(oacc[n][r]);
          }
        }
    }
    __syncthreads();
  }
}

// ---------------- host launcher ----------------
extern "C" void kernel_launch(void* const* d_in, const int* in_sizes, int n_in,
                              void* d_out, int out_size, void* d_ws, size_t ws_size,
                              hipStream_t stream)
{
  const float* x       = (const float*)d_in[0];
  const float* tok_w   = (const float*)d_in[1];
  const float* tok_b   = (const float*)d_in[2];
  const float* cat_emb = (const float*)d_in[3];
  const float* Wqkv    = (const float*)d_in[4];
  const float* bqkv    = (const float*)d_in[5];
  const float* Wout    = (const float*)d_in[6];
  const float* bout    = (const float*)d_in[7];
  const float* W0      = (const float*)d_in[8];
  const float* b0      = (const float*)d_in[9];
  const float* W1      = (const float*)d_in[10];
  const float* b1      = (const float*)d_in[11];
  const float* ln0_g   = (const float*)d_in[12];
  const float* ln0_b   = (const float*)d_in[13];
  const float* ln1_g   = (const float*)d_in[14];
  const float* ln1_b   = (const float*)d_in[15];

  size_t off = 0;
  char* base = (char*)d_ws;
  auto alloc = [&](size_t n) { char* p = base + off; off += (n + 255) & ~(size_t)255; return p; };
  float*  h     = (float*) alloc((size_t)M_ROWS * 512 * 4);
  bf16_t* ab    = (bf16_t*)alloc((size_t)M_ROWS * 512 * 2);   // LN out, frag KT=16
  bf16_t* qkv   = (bf16_t*)alloc((size_t)M_ROWS * 1536 * 2);  // frag KT=48
  bf16_t* attno = (bf16_t*)alloc((size_t)M_ROWS * 512 * 2);   // frag KT=16
  bf16_t* regl  = (bf16_t*)alloc((size_t)M_ROWS * 704 * 2);   // frag KT=22
  bf16_t* WqkvT = (bf16_t*)alloc((size_t)6 * 1536 * 512 * 2);
  bf16_t* WoutT = (bf16_t*)alloc((size_t)6 * 512 * 512 * 2);
  bf16_t* W0T   = (bf16_t*)alloc((size_t)6 * 1408 * 512 * 2);  // pair-interleaved
  bf16_t* W1T   = (bf16_t*)alloc((size_t)6 * 512 * 704 * 2);
  (void)ws_size; (void)in_sizes; (void)n_in; (void)out_size;

  dim3 tb(32, 8, 1);
  transpose_cvt<0><<<dim3(16, 48, 6), tb, 0, stream>>>(Wqkv, WqkvT, 512, 1536, 512, 1536);
  transpose_cvt<0><<<dim3(16, 16, 6), tb, 0, stream>>>(Wout, WoutT, 512, 512, 512, 512);
  transpose_cvt<1><<<dim3(16, 44, 6), tb, 0, stream>>>(W0, W0T, 512, 1364, 512, 1408);
  transpose_cvt<0><<<dim3(22, 16, 6), tb, 0, stream>>>(W1, W1T, 682, 512, 704, 512);

  tokenizer_kernel<<<M_ROWS / 4, 256, 0, stream>>>(x, tok_w, tok_b, cat_emb, h, ab);

  const int GLN = M_ROWS / 32;  // 516
  for (int i = 0; i < 6; i++) {
    gemm_frag<0><<<dim3(12, 129), 256, 0, stream>>>(
        ab, WqkvT + (size_t)i * 1536 * 512, bqkv + (size_t)i * 1536, 1536, nullptr, qkv, 512, 1536);
    attn_kernel<<<1024, 256, 0, stream>>>(qkv, attno);
    // Wout + residual -> h, fused with ln1 -> ab
    gemm_ln<1, 0><<<GLN, 512, 0, stream>>>(
        attno, WoutT + (size_t)i * 512 * 512, bout + (size_t)i * 512, h, h,
        ln1_g + (size_t)i * 512, ln1_b + (size_t)i * 512, ab, nullptr, 512);
    gemm_frag<2><<<dim3(11, 129), 256, 0, stream>>>(
        ab, W0T + (size_t)i * 1408 * 512, b0 + (size_t)i * 1364, 1364, nullptr, regl, 512, 1408);
    // W1 + residual -> h, fused with next layer's ln0 -> ab (or CLS output on last layer)
    if (i < 5)
      gemm_ln<1, 0><<<GLN, 512, 0, stream>>>(
          regl, W1T + (size_t)i * 512 * 704, b1 + (size_t)i * 512, h, h,
          ln0_g + (size_t)(i + 1) * 512, ln0_b + (size_t)(i + 1) * 512, ab, nullptr, 704);
    else
      gemm_ln<0, 1><<<GLN, 512, 0, stream>>>(
          regl, W1T + (size_t)i * 512 * 704, b1 + (size_t)i * 512, h, h,
          nullptr, nullptr, nullptr, (float*)d_out, 704);
  }
}

// Round 8
// 1295.709 us; speedup vs baseline: 1.0070x; 1.0070x over previous
//
#include <hip/hip_runtime.h>
#include <hip/hip_bf16.h>
#include <stdint.h>

// FT-Transformer forward, MI355X gfx950. Round 13:
//  - gemm_frag (QKV, W0): EXACT round-9 best config (both operands via 2-buf
//    global_load_lds LDS, 128x128, 4 waves, (256,4), C^T vectorized epilogue).
//  - gemm_ln v2 (Wout+ln1, W1+next ln0, last W1+CLS out): fusion kept from round 12
//    but the GEMM engine replaced with the PROVEN r9 loop: 64 rows x full N=512,
//    8 waves (wave 64x64, acc[4][4]), LDS-staged A(4ch)+B(32ch), 2-buf,
//    one __syncthreads per k-step, 2 blocks/CU (LDS 76.5KB, launch_bounds(512,4)).
//    r12's barrier-free direct-load engine was latency-bound (50us, MfmaUtil 8%).
//  - ln_kernel + out_copy eliminated (47 -> 35 kernel launches).

typedef __hip_bfloat16 bf16_t;
typedef __attribute__((ext_vector_type(8))) __bf16 bf16x8;
typedef __attribute__((ext_vector_type(4))) __bf16 bf16x4;
typedef __attribute__((ext_vector_type(2))) __bf16 bf16x2;
typedef __attribute__((ext_vector_type(4))) float floatx4;

constexpr int M_ROWS = 16512;          // 128 * 129
constexpr float SQRT_EMB_F = 22.627416997969522f;  // scores DIVIDED by emb**-0.5

__device__ __forceinline__ floatx4 mfma16(bf16x8 a, bf16x8 b, floatx4 c) {
  return __builtin_amdgcn_mfma_f32_16x16x32_bf16(a, b, c, 0, 0, 0);
}

__device__ __forceinline__ void gload_lds16(const bf16_t* g, bf16_t* l) {
  __builtin_amdgcn_global_load_lds(
      (const __attribute__((address_space(1))) void*)g,
      (__attribute__((address_space(3))) void*)l, 16, 0, 0);
}

// element offset of the 16B chunk holding (m, k..k+7) in fragment-tiled [M/16][KT][512]
__device__ __forceinline__ size_t frag_chunk(int m, int k, int KT) {
  return ((size_t)(m >> 4) * KT + (k >> 5)) * 512 + (m & 15) * 8 + 128 * ((k >> 3) & 3);
}
// element offset of scalar (m, k)
__device__ __forceinline__ size_t frag_elem(int m, int k, int KT) {
  return frag_chunk(m, k, KT) + (k & 7);
}

// ---------------- weight transform: W [L][K][N] fp32 -> frag-tiled bf16 [L][N/16][KP/32][512]
// PERM=1: output col n maps to source col (n&1) ? 682+(n>>1) : (n>>1)  (ReGLU pairing)
template <int PERM>
__global__ __launch_bounds__(256) void transpose_cvt(const float* __restrict__ W,
    bf16_t* __restrict__ WT, int K, int N, int KP, int NP)
{
  __shared__ float tile[32][33];
  int k0 = blockIdx.x * 32, n0 = blockIdx.y * 32;
  const float* Wl = W + (size_t)blockIdx.z * K * N;
  bf16_t* WTl = WT + (size_t)blockIdx.z * NP * KP;
  const int KT = KP >> 5;
  #pragma unroll
  for (int r = 0; r < 32; r += 8) {
    int k = k0 + threadIdx.y + r, n = n0 + threadIdx.x;
    int srcn = PERM ? ((n & 1) ? 682 + (n >> 1) : (n >> 1)) : n;
    int valid = (k < K) && (PERM ? (n < 1364) : (n < N));
    tile[threadIdx.y + r][threadIdx.x] = valid ? Wl[(size_t)k * N + srcn] : 0.f;
  }
  __syncthreads();
  #pragma unroll
  for (int r = 0; r < 32; r += 8) {
    int n = n0 + threadIdx.y + r, k = k0 + threadIdx.x;
    if (n < NP && k < KP)
      WTl[frag_elem(n, k, KT)] = __float2bfloat16(tile[threadIdx.x][threadIdx.y + r]);
  }
}

// ---------------- feature tokenizer: wave per row; h row-major fp32 + ab frag bf16 ----------------
__global__ __launch_bounds__(256) void tokenizer_kernel(const float* __restrict__ x,
    const float* __restrict__ tok_w, const float* __restrict__ tok_b,
    const float* __restrict__ cat_emb, float* __restrict__ h, bf16_t* __restrict__ ab)
{
  int row = blockIdx.x * 4 + (threadIdx.x >> 6);
  int lane = threadIdx.x & 63, e0 = lane * 8;
  int b = row / 129, t = row - b * 129;
  float v[8];
  if (t == 0) {
    #pragma unroll
    for (int u = 0; u < 8; u++) v[u] = tok_w[e0 + u];
  } else if (t <= 100) {
    float xv = x[(size_t)b * 128 + 28 + (t - 1)];
    const float* wp = tok_w + (size_t)t * 512 + e0;
    const float* bp = tok_b + (size_t)(t - 1) * 512 + e0;
    #pragma unroll
    for (int u = 0; u < 8; u++) v[u] = wp[u] * xv + bp[u];
  } else {
    int j = t - 101;
    int idx = (int)x[(size_t)b * 128 + j] + 100 * j;
    const float* cp = cat_emb + (size_t)idx * 512 + e0;
    const float* bp = tok_b + (size_t)(t - 1) * 512 + e0;
    #pragma unroll
    for (int u = 0; u < 8; u++) v[u] = cp[u] + bp[u];
  }
  float* hr = h + (size_t)row * 512 + e0;
  #pragma unroll
  for (int u = 0; u < 8; u++) hr[u] = v[u];
  bf16x8 o8;
  #pragma unroll
  for (int u = 0; u < 8; u++) o8[u] = (__bf16)__float2bfloat16(v[u]);
  *(bf16x8*)(ab + ((size_t)(row >> 4) * 16 + (lane >> 2)) * 512 + (row & 15) * 8 + 128 * (lane & 3)) = o8;
}

// ---------------- frag GEMM (QKV / W0): 128x128 block, 4 waves, 2-buf LDS (r9 best) ----------------
// MODE 0: out bf16 frag-tiled (KT_out = N/32).
// MODE 2: ReGLU pairs thread-local, out bf16 frag-tiled [M/16][(N/2)/32][512].
template <int MODE>
__global__ __launch_bounds__(256, 4) void gemm_frag(const bf16_t* __restrict__ A,
    const bf16_t* __restrict__ BT, const float* __restrict__ bias, int biasN,
    void* __restrict__ outp, int K, int N)
{
  __shared__ bf16_t lsA[2][8][512];   // 16 KB
  __shared__ bf16_t lsB[2][8][512];   // 16 KB

  // XCD-aware remap: blocks with lin%8==x get a contiguous idx chunk
  const int total = gridDim.x * gridDim.y;
  const int lin = blockIdx.y * gridDim.x + blockIdx.x;
  const int xcd = lin & 7, kb2 = lin >> 3;
  const int qch = total >> 3, rch = total & 7;
  const int idx = xcd * qch + (xcd < rch ? xcd : rch) + kb2;
  const int bm = idx / gridDim.x;
  const int bn = idx - bm * gridDim.x;
  const int m0 = bm * 128, n0 = bn * 128;

  const int tid = threadIdx.x;
  const int w = tid >> 6, l = tid & 63, l15 = l & 15, quad = l >> 4;
  const int wm = (w >> 1) * 64, wn = (w & 1) * 64;
  const int KT = K >> 5;

  const bf16_t* gA0 = A  + ((size_t)((m0 >> 4) + 2 * w) * KT) * 512 + l * 8;
  const bf16_t* gA1 = gA0 + (size_t)KT * 512;
  const bf16_t* gB0 = BT + ((size_t)((n0 >> 4) + 2 * w) * KT) * 512 + l * 8;
  const bf16_t* gB1 = gB0 + (size_t)KT * 512;
  const int sa = w * 2;
  const int ra = (w >> 1) * 4;
  const int rb = (w & 1) * 4;

  auto stage = [&](int buf, int t) {
    const size_t go = (size_t)t * 512;
    gload_lds16(gA0 + go, &lsA[buf][sa][0]);
    gload_lds16(gA1 + go, &lsA[buf][sa + 1][0]);
    gload_lds16(gB0 + go, &lsB[buf][sa][0]);
    gload_lds16(gB1 + go, &lsB[buf][sa + 1][0]);
  };

  floatx4 z4 = {0.f, 0.f, 0.f, 0.f};
  floatx4 acc[4][4];
  #pragma unroll
  for (int i = 0; i < 4; i++)
    #pragma unroll
    for (int j = 0; j < 4; j++) acc[i][j] = z4;

  stage(0, 0);
  __syncthreads();

  int cur = 0;
  for (int t = 0; t < KT; ++t) {
    if (t + 1 < KT) stage(cur ^ 1, t + 1);
    bf16x8 af[4], bg[4];
    #pragma unroll
    for (int i = 0; i < 4; i++) {
      af[i] = *(const bf16x8*)&lsA[cur][ra + i][l * 8];
      bg[i] = *(const bf16x8*)&lsB[cur][rb + i][l * 8];
    }
    #pragma unroll
    for (int i = 0; i < 4; i++)
      #pragma unroll
      for (int j = 0; j < 4; j++)
        acc[i][j] = mfma16(bg[j], af[i], acc[i][j]);   // C^T
    __syncthreads();
    cur ^= 1;
  }

  // epilogue: thread owns rows m = m0+wm+i*16+l15, cols nb..nb+3 (consecutive)
  #pragma unroll
  for (int i = 0; i < 4; i++) {
    int m = m0 + wm + i * 16 + l15;
    #pragma unroll
    for (int j = 0; j < 4; j++) {
      int nb = n0 + wn + j * 16 + quad * 4;
      if (MODE == 2) {
        int c2b = nb >> 1;
        bf16x2 o2;
        #pragma unroll
        for (int u = 0; u < 2; u++) {
          int c2 = c2b + u;
          bool vld = (2 * c2 < biasN);
          float av = acc[i][j][2 * u]     + (vld ? bias[c2] : 0.f);
          float bv = acc[i][j][2 * u + 1] + (vld ? bias[682 + c2] : 0.f);
          o2[u] = (__bf16)__float2bfloat16(av * fmaxf(bv, 0.f));
        }
        *(bf16x2*)&((bf16_t*)outp)[frag_elem(m, c2b, (N >> 1) >> 5)] = o2;
      } else {
        bf16x4 o4;
        #pragma unroll
        for (int r = 0; r < 4; r++) {
          float bv = (nb + r < biasN) ? bias[nb + r] : 0.f;
          o4[r] = (__bf16)__float2bfloat16(acc[i][j][r] + bv);
        }
        *(bf16x4*)&((bf16_t*)outp)[frag_elem(m, nb, N >> 5)] = o4;
      }
    }
  }
}

// ---------------- fused GEMM + residual + LayerNorm (r9-engine): 64 rows x full N=512 ----
// 8 waves; wave tile 64x64 (acc[4][4], same as gemm_frag). A (4 chunks) + B (32 chunks)
// staged via 2-buf global_load_lds; one __syncthreads per k-step; 2 blocks/CU.
// Epilogue: h = acc + bias + resid (fp32); LN over full row via quad-shuffle + LDS
// cross-wave reduce -> ab (bf16 frag, KT=16).
// DOLN=0: skip LN/ab. DOOUT=1: skip h write; emit CLS rows (m%129==0) to outp.
template <int DOLN, int DOOUT>
__global__ __launch_bounds__(512, 4) void gemm_ln(const bf16_t* __restrict__ A,
    const bf16_t* __restrict__ BT, const float* __restrict__ bias,
    const float* __restrict__ resid, float* __restrict__ hout,
    const float* __restrict__ g, const float* __restrict__ beta,
    bf16_t* __restrict__ ab, float* __restrict__ outp, int K)
{
  __shared__ bf16_t lsA[2][4][512];    // 8 KB
  __shared__ bf16_t lsB[2][32][512];   // 64 KB
  __shared__ float lnred[2][8][64];    // 4 KB

  // XCD-aware bijective remap (1-D grid)
  const int nwg = gridDim.x;
  const int lin = blockIdx.x;
  const int xcd = lin & 7, kb2 = lin >> 3;
  const int qch = nwg >> 3, rch = nwg & 7;
  const int idx = xcd * qch + (xcd < rch ? xcd : rch) + kb2;
  const int m0 = idx * 64;

  const int tid = threadIdx.x;
  const int w = tid >> 6, l = tid & 63, l15 = l & 15, quad = l >> 4;
  const int wn = w * 64;
  const int KT = K >> 5;

  // staging: wave w stages B col-tiles {4w..4w+3}; waves 0-3 also stage A tile w
  const bf16_t* gB[4];
  #pragma unroll
  for (int s = 0; s < 4; s++)
    gB[s] = BT + ((size_t)(4 * w + s) * KT) * 512 + l * 8;
  const bf16_t* gA = A + ((size_t)((m0 >> 4) + (w & 3)) * KT) * 512 + l * 8;

  auto stage = [&](int buf, int t) {
    const size_t go = (size_t)t * 512;
    #pragma unroll
    for (int s = 0; s < 4; s++) gload_lds16(gB[s] + go, &lsB[buf][4 * w + s][0]);
    if (w < 4) gload_lds16(gA + go, &lsA[buf][w][0]);
  };

  floatx4 acc[4][4];
  #pragma unroll
  for (int i = 0; i < 4; i++)
    #pragma unroll
    for (int j = 0; j < 4; j++) acc[i][j] = floatx4{0.f, 0.f, 0.f, 0.f};

  stage(0, 0);
  __syncthreads();

  int cur = 0;
  for (int t = 0; t < KT; ++t) {
    if (t + 1 < KT) stage(cur ^ 1, t + 1);
    bf16x8 af[4], bg[4];
    #pragma unroll
    for (int i = 0; i < 4; i++) af[i] = *(const bf16x8*)&lsA[cur][i][l * 8];
    #pragma unroll
    for (int j = 0; j < 4; j++) bg[j] = *(const bf16x8*)&lsB[cur][w * 4 + j][l * 8];
    #pragma unroll
    for (int i = 0; i < 4; i++)
      #pragma unroll
      for (int j = 0; j < 4; j++)
        acc[i][j] = mfma16(bg[j], af[i], acc[i][j]);   // C^T: l15 = row, quad*4+r = col
    __syncthreads();
    cur ^= 1;
  }

  // ---- epilogue: h = acc + bias + resid; LN partials ----
  const int colb = wn + quad * 4;
  float s[4], q[4];
  #pragma unroll
  for (int i = 0; i < 4; i++) {
    const int m = m0 + i * 16 + l15;
    const float* rr = resid + (size_t)m * 512;
    s[i] = 0.f; q[i] = 0.f;
    #pragma unroll
    for (int j = 0; j < 4; j++) {
      const int nb = colb + j * 16;
      float4 rv = *(const float4*)(rr + nb);
      float4 bv = *(const float4*)(bias + nb);
      floatx4 hv;
      hv[0] = acc[i][j][0] + bv.x + rv.x;
      hv[1] = acc[i][j][1] + bv.y + rv.y;
      hv[2] = acc[i][j][2] + bv.z + rv.z;
      hv[3] = acc[i][j][3] + bv.w + rv.w;
      acc[i][j] = hv;
      float4 hw = {hv[0], hv[1], hv[2], hv[3]};
      if (!DOOUT) *(float4*)(hout + (size_t)m * 512 + nb) = hw;
      if (DOOUT) {
        if (m % 129 == 0)
          *(float4*)(outp + (size_t)(m / 129) * 512 + nb) = hw;
      }
      s[i] += hv[0] + hv[1] + hv[2] + hv[3];
      q[i] += hv[0] * hv[0] + hv[1] * hv[1] + hv[2] * hv[2] + hv[3] * hv[3];
    }
  }

  if (DOLN) {
    #pragma unroll
    for (int i = 0; i < 4; i++) {
      s[i] += __shfl_xor(s[i], 16); s[i] += __shfl_xor(s[i], 32);
      q[i] += __shfl_xor(q[i], 16); q[i] += __shfl_xor(q[i], 32);
    }
    if (quad == 0) {
      #pragma unroll
      for (int i = 0; i < 4; i++) {
        lnred[0][w][i * 16 + l15] = s[i];
        lnred[1][w][i * 16 + l15] = q[i];
      }
    }
    __syncthreads();
    #pragma unroll
    for (int i = 0; i < 4; i++) {
      const int m = m0 + i * 16 + l15;
      float ss = 0.f, qq = 0.f;
      #pragma unroll
      for (int wv = 0; wv < 8; wv++) {
        ss += lnred[0][wv][i * 16 + l15];
        qq += lnred[1][wv][i * 16 + l15];
      }
      float mean = ss * (1.f / 512.f);
      float var = qq * (1.f / 512.f) - mean * mean;
      float rstd = rsqrtf(var + 1e-5f);
      #pragma unroll
      for (int j = 0; j < 4; j++) {
        const int nb = colb + j * 16;
        float4 gg = *(const float4*)(g + nb);
        float4 bb = *(const float4*)(beta + nb);
        bf16x4 o4;
        o4[0] = (__bf16)__float2bfloat16((acc[i][j][0] - mean) * rstd * gg.x + bb.x);
        o4[1] = (__bf16)__float2bfloat16((acc[i][j][1] - mean) * rstd * gg.y + bb.y);
        o4[2] = (__bf16)__float2bfloat16((acc[i][j][2] - mean) * rstd * gg.z + bb.z);
        o4[3] = (__bf16)__float2bfloat16((acc[i][j][3] - mean) * rstd * gg.w + bb.w);
        *(bf16x4*)&ab[frag_elem(m, nb, 16)] = o4;
      }
    }
  }
}

// ---------------- fused attention: one block per (batch, head) ----------------
// qkv frag-tiled over [M, 1536] (KT=48); head hh: q at col hh*192, k +64, v +128.
constexpr int SP = 160;  // S=129 padded to 5*32
__global__ __launch_bounds__(256) void attn_kernel(const bf16_t* __restrict__ qkv,
                                                   bf16_t* __restrict__ attnout)
{
  __shared__ bf16_t vt_lds[64 * SP];   // [d][s_kv]
  __shared__ float sc[32 * SP];        // scores; p (bf16) overlays
  bf16_t* p_lds = (bf16_t*)sc;
  __bf16* vt_raw = (__bf16*)vt_lds;

  const int bh = blockIdx.x, b = bh >> 3, hh = bh & 7;
  const int tid = threadIdx.x;
  const int w = tid >> 6, l = tid & 63, l15 = l & 15, quad = l >> 4;
  const int rbase = b * 129;

  for (int i = tid; i < SP * 64 / 2; i += 256) ((unsigned int*)vt_lds)[i] = 0u;
  __syncthreads();
  for (int c = tid; c < 129 * 8; c += 256) {
    int s = c >> 3, ch = c & 7;
    bf16x8 tv = *(const bf16x8*)(qkv + frag_chunk(rbase + s, hh * 192 + 128 + ch * 8, 48));
    #pragma unroll
    for (int j = 0; j < 8; j++) vt_raw[(size_t)(ch * 8 + j) * SP + s] = tv[j];
  }
  __syncthreads();

  for (int qt = 0; qt < 5; qt++) {
    bf16x8 zq = {};
    bf16x8 aq[2][2];
    #pragma unroll
    for (int mt = 0; mt < 2; mt++) {
      int m = qt * 32 + mt * 16 + l15;
      #pragma unroll
      for (int t = 0; t < 2; t++)
        aq[mt][t] = (m < 129)
            ? *(const bf16x8*)(qkv + frag_chunk(rbase + m, hh * 192 + t * 32 + quad * 8, 48)) : zq;
    }
    for (int nt = w; nt < 10; nt += 4) {
      int krow = nt * 16 + l15;
      floatx4 a0 = {0.f, 0.f, 0.f, 0.f}, a1 = {0.f, 0.f, 0.f, 0.f};
      #pragma unroll
      for (int t = 0; t < 2; t++) {
        bf16x8 kf = (krow < 129)
            ? *(const bf16x8*)(qkv + frag_chunk(rbase + krow, hh * 192 + 64 + t * 32 + quad * 8, 48))
            : zq;
        a0 = mfma16(aq[0][t], kf, a0);
        a1 = mfma16(aq[1][t], kf, a1);
      }
      #pragma unroll
      for (int r = 0; r < 4; r++) {
        sc[(quad * 4 + r) * SP + nt * 16 + l15]      = a0[r] * SQRT_EMB_F;
        sc[(16 + quad * 4 + r) * SP + nt * 16 + l15] = a1[r] * SQRT_EMB_F;
      }
    }
    __syncthreads();

    // double softmax, 8 threads per row
    {
      int row = tid >> 3, sub = tid & 7;
      float vv[20];
      float mx = -1e30f;
      #pragma unroll
      for (int c = 0; c < 20; c++) {
        int j = sub + c * 8;
        vv[c] = (j < 129) ? sc[row * SP + j] : -1e30f;
        mx = fmaxf(mx, vv[c]);
      }
      #pragma unroll
      for (int o = 1; o < 8; o <<= 1) mx = fmaxf(mx, __shfl_xor(mx, o, 8));
      float sum = 0.f;
      #pragma unroll
      for (int c = 0; c < 20; c++) {
        int j = sub + c * 8;
        vv[c] = (j < 129) ? __expf(vv[c] - mx) : 0.f;
        sum += vv[c];
      }
      #pragma unroll
      for (int o = 1; o < 8; o <<= 1) sum += __shfl_xor(sum, o, 8);
      float inv = 1.f / sum;
      float mx2 = 0.f;
      #pragma unroll
      for (int c = 0; c < 20; c++) { vv[c] *= inv; mx2 = fmaxf(mx2, vv[c]); }
      #pragma unroll
      for (int o = 1; o < 8; o <<= 1) mx2 = fmaxf(mx2, __shfl_xor(mx2, o, 8));
      float sum2 = 0.f;
      #pragma unroll
      for (int c = 0; c < 20; c++) {
        int j = sub + c * 8;
        vv[c] = (j < 129) ? __expf(vv[c] - mx2) : 0.f;
        sum2 += vv[c];
      }
      #pragma unroll
      for (int o = 1; o < 8; o <<= 1) sum2 += __shfl_xor(sum2, o, 8);
      float inv2 = 1.f / sum2;
      __syncthreads();
      #pragma unroll
      for (int c = 0; c < 20; c++) {
        int j = sub + c * 8;
        p_lds[row * SP + j] = __float2bfloat16(vv[c] * inv2);  // pads -> 0
      }
    }
    __syncthreads();

    // PV: o[32,64] = p[32,160] @ v[160,64]; store attno in frag layout (KT=16)
    {
      int mt = w >> 1, nt0 = (w & 1) * 2;
      floatx4 oacc[2];
      oacc[0] = floatx4{0.f, 0.f, 0.f, 0.f};
      oacc[1] = floatx4{0.f, 0.f, 0.f, 0.f};
      #pragma unroll
      for (int t = 0; t < 5; t++) {
        bf16x8 pf = *(const bf16x8*)&p_lds[(mt * 16 + l15) * SP + t * 32 + quad * 8];
        #pragma unroll
        for (int n = 0; n < 2; n++) {
          bf16x8 vf = *(const bf16x8*)&vt_lds[((nt0 + n) * 16 + l15) * SP + t * 32 + quad * 8];
          oacc[n] = mfma16(pf, vf, oacc[n]);
        }
      }
      #pragma unroll
      for (int n = 0; n < 2; n++)
        #pragma unroll
        for (int r = 0; r < 4; r++) {
          int sq = qt * 32 + mt * 16 + quad * 4 + r;
          if (sq < 129) {
            int cc = hh * 64 + (nt0 + n) * 16 + l15;
            attnout[frag_elem(rbase + sq, cc, 16)] = __float2bfloat16(oacc[n][r]);
          }
        }
    }
    __syncthreads();
  }
}

// ---------------- host launcher ----------------
extern "C" void kernel_launch(void* const* d_in, const int* in_sizes, int n_in,
                              void* d_out, int out_size, void* d_ws, size_t ws_size,
                              hipStream_t stream)
{
  const float* x       = (const float*)d_in[0];
  const float* tok_w   = (const float*)d_in[1];
  const float* tok_b   = (const float*)d_in[2];
  const float* cat_emb = (const float*)d_in[3];
  const float* Wqkv    = (const float*)d_in[4];
  const float* bqkv    = (const float*)d_in[5];
  const float* Wout    = (const float*)d_in[6];
  const float* bout    = (const float*)d_in[7];
  const float* W0      = (const float*)d_in[8];
  const float* b0      = (const float*)d_in[9];
  const float* W1      = (const float*)d_in[10];
  const float* b1      = (const float*)d_in[11];
  const float* ln0_g   = (const float*)d_in[12];
  const float* ln0_b   = (const float*)d_in[13];
  const float* ln1_g   = (const float*)d_in[14];
  const float* ln1_b   = (const float*)d_in[15];

  size_t off = 0;
  char* base = (char*)d_ws;
  auto alloc = [&](size_t n) { char* p = base + off; off += (n + 255) & ~(size_t)255; return p; };
  float*  h     = (float*) alloc((size_t)M_ROWS * 512 * 4);
  bf16_t* ab    = (bf16_t*)alloc((size_t)M_ROWS * 512 * 2);   // LN out, frag KT=16
  bf16_t* qkv   = (bf16_t*)alloc((size_t)M_ROWS * 1536 * 2);  // frag KT=48
  bf16_t* attno = (bf16_t*)alloc((size_t)M_ROWS * 512 * 2);   // frag KT=16
  bf16_t* regl  = (bf16_t*)alloc((size_t)M_ROWS * 704 * 2);   // frag KT=22
  bf16_t* WqkvT = (bf16_t*)alloc((size_t)6 * 1536 * 512 * 2);
  bf16_t* WoutT = (bf16_t*)alloc((size_t)6 * 512 * 512 * 2);
  bf16_t* W0T   = (bf16_t*)alloc((size_t)6 * 1408 * 512 * 2);  // pair-interleaved
  bf16_t* W1T   = (bf16_t*)alloc((size_t)6 * 512 * 704 * 2);
  (void)ws_size; (void)in_sizes; (void)n_in; (void)out_size;

  dim3 tb(32, 8, 1);
  transpose_cvt<0><<<dim3(16, 48, 6), tb, 0, stream>>>(Wqkv, WqkvT, 512, 1536, 512, 1536);
  transpose_cvt<0><<<dim3(16, 16, 6), tb, 0, stream>>>(Wout, WoutT, 512, 512, 512, 512);
  transpose_cvt<1><<<dim3(16, 44, 6), tb, 0, stream>>>(W0, W0T, 512, 1364, 512, 1408);
  transpose_cvt<0><<<dim3(22, 16, 6), tb, 0, stream>>>(W1, W1T, 682, 512, 704, 512);

  tokenizer_kernel<<<M_ROWS / 4, 256, 0, stream>>>(x, tok_w, tok_b, cat_emb, h, ab);

  const int GLN = M_ROWS / 64;  // 258
  for (int i = 0; i < 6; i++) {
    gemm_frag<0><<<dim3(12, 129), 256, 0, stream>>>(
        ab, WqkvT + (size_t)i * 1536 * 512, bqkv + (size_t)i * 1536, 1536, qkv, 512, 1536);
    attn_kernel<<<1024, 256, 0, stream>>>(qkv, attno);
    // Wout + residual -> h, fused with ln1 -> ab
    gemm_ln<1, 0><<<GLN, 512, 0, stream>>>(
        attno, WoutT + (size_t)i * 512 * 512, bout + (size_t)i * 512, h, h,
        ln1_g + (size_t)i * 512, ln1_b + (size_t)i * 512, ab, nullptr, 512);
    gemm_frag<2><<<dim3(11, 129), 256, 0, stream>>>(
        ab, W0T + (size_t)i * 1408 * 512, b0 + (size_t)i * 1364, 1364, regl, 512, 1408);
    // W1 + residual -> h, fused with next layer's ln0 -> ab (or CLS output on last layer)
    if (i < 5)
      gemm_ln<1, 0><<<GLN, 512, 0, stream>>>(
          regl, W1T + (size_t)i * 512 * 704, b1 + (size_t)i * 512, h, h,
          ln0_g + (size_t)(i + 1) * 512, ln0_b + (size_t)(i + 1) * 512, ab, nullptr, 704);
    else
      gemm_ln<0, 1><<<GLN, 512, 0, stream>>>(
          regl, W1T + (size_t)i * 512 * 704, b1 + (size_t)i * 512, h, h,
          nullptr, nullptr, nullptr, (float*)d_out, 704);
  }
}